// Round 4
// baseline (632.558 us; speedup 1.0000x reference)
//
#include <hip/hip_runtime.h>
#include <hip/hip_bf16.h>
#include <math.h>

#define NN 50000
#define NE 800000
#define NK 4
#define FD 128
#define CD 32
#define NCHUNK 196   // ceil(NN/256)
#define BNCH 25      // bn stat chunks
#define BNROWS 2000  // rows per bn chunk (25*2000 = 50000)

typedef unsigned short u16;

__device__ __forceinline__ u16 f2bf(float x) {
    union { float f; unsigned u; } c; c.f = x;
    unsigned r = c.u + 0x7fffu + ((c.u >> 16) & 1u);  // RNE
    return (u16)(r >> 16);
}
__device__ __forceinline__ float bf2f(unsigned bits) {
    union { unsigned u; float f; } c; c.u = bits << 16;
    return c.f;
}

// ---------------- CSR build ----------------

__global__ void k_count(const int* __restrict__ dst, int* __restrict__ count) {
    int i = blockIdx.x * 256 + threadIdx.x;
    if (i < NE) atomicAdd(&count[dst[i]], 1);
}

__global__ void k_chunksum(const int* __restrict__ count, int* __restrict__ csum) {
    __shared__ int s[256];
    int tid = threadIdx.x;
    int i = blockIdx.x * 256 + tid;
    s[tid] = (i < NN) ? count[i] : 0;
    __syncthreads();
    for (int off = 128; off > 0; off >>= 1) {
        if (tid < off) s[tid] += s[tid + off];
        __syncthreads();
    }
    if (tid == 0) csum[blockIdx.x] = s[0];
}

__global__ void k_scan_csum(int* __restrict__ csum) {
    __shared__ int s[256];
    int tid = threadIdx.x;
    int v = (tid < NCHUNK) ? csum[tid] : 0;
    s[tid] = v;
    __syncthreads();
    for (int off = 1; off < 256; off <<= 1) {
        int t = 0;
        if (tid >= off) t = s[tid - off];
        __syncthreads();
        s[tid] += t;
        __syncthreads();
    }
    if (tid < NCHUNK) csum[tid] = s[tid] - v;  // exclusive
}

__global__ void k_scan_final(const int* __restrict__ count, const int* __restrict__ csum,
                             int* __restrict__ rowstart, int* __restrict__ cursor) {
    __shared__ int s[256];
    int tid = threadIdx.x;
    int i = blockIdx.x * 256 + tid;
    int v = (i < NN) ? count[i] : 0;
    s[tid] = v;
    __syncthreads();
    for (int off = 1; off < 256; off <<= 1) {
        int t = 0;
        if (tid >= off) t = s[tid - off];
        __syncthreads();
        s[tid] += t;
        __syncthreads();
    }
    int incl = s[tid];
    int base = csum[blockIdx.x];
    int excl = base + incl - v;
    if (i < NN) {
        rowstart[i] = excl;
        cursor[i] = excl;
        if (i == NN - 1) rowstart[NN] = excl + v;
    }
}

// one packed scattered stream: {src, w01 (bf16 k0|k1), w23 (bf16 k2|k3), pad}
__global__ void k_scatter(const int* __restrict__ src, const int* __restrict__ dst,
                          const float* __restrict__ ew,
                          int* __restrict__ cursor, int4* __restrict__ sse) {
    int e = blockIdx.x * 256 + threadIdx.x;
    if (e < NE) {
        int d = dst[e];
        int p = atomicAdd(&cursor[d], 1);
        unsigned w01 = (unsigned)f2bf(ew[e]) | ((unsigned)f2bf(ew[(size_t)NE + e]) << 16);
        unsigned w23 = (unsigned)f2bf(ew[(size_t)2 * NE + e]) | ((unsigned)f2bf(ew[(size_t)3 * NE + e]) << 16);
        sse[p] = make_int4(src[e], (int)w01, (int)w23, 0);
    }
}

// ---------------- fused encoder + y0 (y0 stored bf16) ----------------

__global__ void __launch_bounds__(256) k_enc_y0(const float* __restrict__ x,
                                                const float* __restrict__ W,
                                                const float* __restrict__ b,
                                                const float* __restrict__ W1,
                                                float* __restrict__ out,
                                                u16* __restrict__ y0) {
    __shared__ float xsT[FD][68];
    int tid = threadIdx.x;
    int nbase = blockIdx.x * 64;

    int r = tid >> 2;
    int cg = (tid & 3) * 32;
    int gn = nbase + r;
    const float* xr = x + (size_t)(gn < NN ? gn : NN - 1) * FD;
#pragma unroll
    for (int q = 0; q < 8; ++q) {
        float4 v = *(const float4*)(xr + cg + q * 4);
        int f = cg + q * 4;
        xsT[f][r] = v.x; xsT[f + 1][r] = v.y; xsT[f + 2][r] = v.z; xsT[f + 3][r] = v.w;
    }
    __syncthreads();

    int cq = (tid & 31) * 4;
    int col = tid & 31;
    int g = tid >> 5;
    float acc[8][4];
    float acy[8];
#pragma unroll
    for (int i = 0; i < 8; ++i) {
        acy[i] = 0.f;
#pragma unroll
        for (int j = 0; j < 4; ++j) acc[i][j] = 0.f;
    }

    for (int f = 0; f < FD; ++f) {
        float4 wv = *(const float4*)(W + f * FD + cq);
        float w1 = W1[f * CD + col];
        float4 xa = *(const float4*)&xsT[f][g * 8];
        float4 xb = *(const float4*)&xsT[f][g * 8 + 4];
        float xn[8] = {xa.x, xa.y, xa.z, xa.w, xb.x, xb.y, xb.z, xb.w};
#pragma unroll
        for (int i = 0; i < 8; ++i) {
            acc[i][0] += xn[i] * wv.x;
            acc[i][1] += xn[i] * wv.y;
            acc[i][2] += xn[i] * wv.z;
            acc[i][3] += xn[i] * wv.w;
            acy[i] += xn[i] * w1;
        }
    }
    float4 bv = *(const float4*)(b + cq);
#pragma unroll
    for (int i = 0; i < 8; ++i) {
        int n = nbase + g * 8 + i;
        if (n < NN) {
            float4 o;
            o.x = acc[i][0] + bv.x;
            o.y = acc[i][1] + bv.y;
            o.z = acc[i][2] + bv.z;
            o.w = acc[i][3] + bv.w;
            *(float4*)(out + (size_t)n * FD + cq) = o;
            y0[(size_t)n * CD + col] = f2bf(acy[i]);
        }
    }
}

// ---------------- y1: per-community h_k @ W1 (32->32), output bf16 [4][N][32] ----------------

__global__ void __launch_bounds__(256) k_y1(const float* __restrict__ h,
                                            const float* __restrict__ W1,
                                            u16* __restrict__ y1) {
    __shared__ float hsT[FD][68];
    int tid = threadIdx.x;
    int nbase = blockIdx.x * 64;

    int r = tid >> 2;
    int cg = (tid & 3) * 32;
    int gn = nbase + r;
    const float* hr = h + (size_t)(gn < NN ? gn : NN - 1) * FD;
#pragma unroll
    for (int q = 0; q < 8; ++q) {
        float4 v = *(const float4*)(hr + cg + q * 4);
        int f = cg + q * 4;
        hsT[f][r] = v.x; hsT[f + 1][r] = v.y; hsT[f + 2][r] = v.z; hsT[f + 3][r] = v.w;
    }
    __syncthreads();

    int c0 = (tid & 31) * 4;
    int g = tid >> 5;
    int kc = c0 >> 5;
    int jb = c0 & 31;
    float acc[8][4];
#pragma unroll
    for (int i = 0; i < 8; ++i)
#pragma unroll
        for (int j = 0; j < 4; ++j) acc[i][j] = 0.f;

    for (int m = 0; m < CD; ++m) {
        float4 wv = *(const float4*)(W1 + m * CD + jb);
        float4 xa = *(const float4*)&hsT[kc * CD + m][g * 8];
        float4 xb = *(const float4*)&hsT[kc * CD + m][g * 8 + 4];
        float xn[8] = {xa.x, xa.y, xa.z, xa.w, xb.x, xb.y, xb.z, xb.w};
#pragma unroll
        for (int i = 0; i < 8; ++i) {
            acc[i][0] += xn[i] * wv.x;
            acc[i][1] += xn[i] * wv.y;
            acc[i][2] += xn[i] * wv.z;
            acc[i][3] += xn[i] * wv.w;
        }
    }
#pragma unroll
    for (int i = 0; i < 8; ++i) {
        int n = nbase + g * 8 + i;
        if (n < NN) {
            unsigned lo = (unsigned)f2bf(acc[i][0]) | ((unsigned)f2bf(acc[i][1]) << 16);
            unsigned hi = (unsigned)f2bf(acc[i][2]) | ((unsigned)f2bf(acc[i][3]) << 16);
            uint2 pk = make_uint2(lo, hi);
            *(uint2*)(y1 + (size_t)kc * NN * CD + (size_t)n * CD + jb) = pk;
        }
    }
}

// ---------------- aggregation + relu + MLP2, community-per-block ----------------
// block = 4 waves = 4 nodes, ONE community per block.
// XCD-aware: k = (blockIdx&7)>>1 -> each XCD's L2 caches one community's 3.2MB plane.
// wave: lane f = lane&31 (feature), hi = lane>>5 splits edge list & MLP2 dot.

__global__ void __launch_bounds__(256) k_aggr(const u16* __restrict__ ytab, int kstride,
                                              const int* __restrict__ row,
                                              const int4* __restrict__ sse,
                                              const float* __restrict__ b1,
                                              const float* __restrict__ W2,
                                              const float* __restrict__ b2,
                                              float* __restrict__ u) {
    __shared__ float W2s[CD][CD + 1];
    __shared__ float tsh[4][CD];
    int tid = threadIdx.x;
    for (int i = tid; i < CD * CD; i += 256) W2s[i >> 5][i & 31] = W2[i];
    __syncthreads();

    int g = blockIdx.x;
    int k = (g & 7) >> 1;                    // community, constant per XCD (mod-8 dispatch)
    int nb = ((g >> 3) << 1) | (g & 1);      // node block 0..12499 (bijective)
    int w = tid >> 6;
    int lane = tid & 63;
    int node = nb * 4 + w;

    int f = lane & 31;
    int hi = lane >> 5;
    const u16* yk = ytab + (size_t)k * kstride;

    float a = 0.f;
    int beg = row[node], end = row[node + 1];
    for (int j0 = beg + hi * 4; j0 < end; j0 += 8) {
        int ss[4];
        float wwv[4];
#pragma unroll
        for (int q = 0; q < 4; ++q) {
            int jj = j0 + q;
            bool ok = jj < end;
            int jc = ok ? jj : beg;
            int4 ee = sse[jc];
            ss[q] = ee.x;
            unsigned wp = (k < 2) ? (unsigned)ee.y : (unsigned)ee.z;
            unsigned wu = (k & 1) ? (wp >> 16) : (wp & 0xffffu);
            wwv[q] = ok ? bf2f(wu) : 0.f;
        }
#pragma unroll
        for (int q = 0; q < 4; ++q) {
            float v = bf2f(yk[(size_t)ss[q] * CD + f]);
            a += wwv[q] * v;
        }
    }
    a += __shfl_xor(a, 32);
    float t = fmaxf(bf2f(yk[(size_t)node * CD + f]) + a + b1[f], 0.f);
    if (hi == 0) tsh[w][f] = t;
    __syncthreads();

    int m0 = hi * 16;
    float up = 0.f;
#pragma unroll
    for (int m = 0; m < 16; ++m) up += tsh[w][m0 + m] * W2s[m0 + m][f];
    up += __shfl_xor(up, 32);
    if (hi == 0) u[((size_t)k * NN + node) * CD + f] = up + b2[f];
}

// ---------------- batchnorm (two-stage, deterministic) ----------------

__global__ void __launch_bounds__(256) k_bn_stats1(const float* __restrict__ u,
                                                   float* __restrict__ part) {
    int k = blockIdx.x & 3;
    int ch = blockIdx.x >> 2;
    int f = threadIdx.x & 31;
    int rg = threadIdx.x >> 5;
    float s1 = 0.f, s2 = 0.f;
    int nend = (ch + 1) * BNROWS;
    if (nend > NN) nend = NN;
    for (int n = ch * BNROWS + rg; n < nend; n += 8) {
        float v = u[((size_t)k * NN + n) * CD + f];
        s1 += v;
        s2 += v * v;
    }
    __shared__ float sh1[8][32], sh2[8][32];
    sh1[rg][f] = s1;
    sh2[rg][f] = s2;
    __syncthreads();
    if (rg == 0) {
#pragma unroll
        for (int r = 1; r < 8; ++r) {
            s1 += sh1[r][f];
            s2 += sh2[r][f];
        }
        part[(((size_t)k * BNCH + ch) * CD + f) * 2] = s1;
        part[(((size_t)k * BNCH + ch) * CD + f) * 2 + 1] = s2;
    }
}

__global__ void k_bn_stats2(const float* __restrict__ part, const float* __restrict__ gamma,
                            const float* __restrict__ beta, float* __restrict__ bnp) {
    int c = threadIdx.x;  // 0..127
    int k = c >> 5, f = c & 31;
    float S1 = 0.f, S2 = 0.f;
    for (int ch = 0; ch < BNCH; ++ch) {
        S1 += part[(((size_t)k * BNCH + ch) * CD + f) * 2];
        S2 += part[(((size_t)k * BNCH + ch) * CD + f) * 2 + 1];
    }
    float mean = S1 / (float)NN;
    float var = S2 / (float)NN - mean * mean;
    float scale = gamma[f] * rsqrtf(var + 1e-5f);
    bnp[c * 2] = scale;
    bnp[c * 2 + 1] = beta[f] - mean * scale;
}

__global__ void __launch_bounds__(256) k_bn_apply(const float* __restrict__ u,
                                                  const float* __restrict__ bnp,
                                                  float* __restrict__ out) {
    int idx = blockIdx.x * 256 + threadIdx.x;  // over NN*FD
    int n = idx >> 7;
    int c = idx & 127;
    int k = c >> 5, f = c & 31;
    float v = u[((size_t)k * NN + n) * CD + f];
    out[idx] = fmaxf(fmaf(v, bnp[c * 2], bnp[c * 2 + 1]), 0.f);
}

// ---------------- launch ----------------

extern "C" void kernel_launch(void* const* d_in, const int* in_sizes, int n_in,
                              void* d_out, int out_size, void* d_ws, size_t ws_size,
                              hipStream_t stream) {
    const float* x = (const float*)d_in[0];
    const int* ei = (const int*)d_in[1];
    const float* ew = (const float*)d_in[2];
    const float* l0W1 = (const float*)d_in[3];
    const float* l0b1 = (const float*)d_in[4];
    const float* l0W2 = (const float*)d_in[5];
    const float* l0b2 = (const float*)d_in[6];
    const float* l0g = (const float*)d_in[7];
    const float* l0be = (const float*)d_in[8];
    const float* l1W1 = (const float*)d_in[9];
    const float* l1b1 = (const float*)d_in[10];
    const float* l1W2 = (const float*)d_in[11];
    const float* l1b2 = (const float*)d_in[12];
    const float* l1g = (const float*)d_in[13];
    const float* l1be = (const float*)d_in[14];
    const float* encW = (const float*)d_in[15];
    const float* encb = (const float*)d_in[16];
    float* out = (float*)d_out;

    char* ws = (char*)d_ws;
    size_t off = 0;
    auto alloc = [&](size_t bytes) -> void* {
        void* p = ws + off;
        off += (bytes + 255) & ~(size_t)255;
        return p;
    };
    int* dcount = (int*)alloc((size_t)NN * 4);
    int* drow = (int*)alloc((size_t)(NN + 1) * 4);
    int* dcur = (int*)alloc((size_t)NN * 4);
    int* dcsum = (int*)alloc(256 * 4);
    int4* dsse = (int4*)alloc((size_t)NE * 16);
    u16* dy0 = (u16*)alloc((size_t)NN * CD * 2);            // bf16 y0 (1.6MB)
    u16* dy1 = (u16*)alloc((size_t)NK * NN * CD * 2);       // bf16 y1 planes (3.2MB each)
    float* du = (float*)alloc((size_t)NK * NN * CD * 4);    // MLP2 out (fp32)
    float* dpart = (float*)alloc((size_t)NK * BNCH * CD * 2 * 4);
    float* dbnp = (float*)alloc((size_t)FD * 2 * 4);

    const int* src = ei;
    const int* dst = ei + NE;

    // CSR build + packed (src, weights) scatter
    hipMemsetAsync(dcount, 0, (size_t)NN * 4, stream);
    k_count<<<(NE + 255) / 256, 256, 0, stream>>>(dst, dcount);
    k_chunksum<<<NCHUNK, 256, 0, stream>>>(dcount, dcsum);
    k_scan_csum<<<1, 256, 0, stream>>>(dcsum);
    k_scan_final<<<NCHUNK, 256, 0, stream>>>(dcount, dcsum, drow, dcur);
    k_scatter<<<(NE + 255) / 256, 256, 0, stream>>>(src, dst, ew, dcur, dsse);

    // plane 0 + y0
    k_enc_y0<<<(NN + 63) / 64, 256, 0, stream>>>(x, encW, encb, l0W1, out, dy0);

    // ---- layer 0 -> plane 1 ----
    float* plane1 = out + (size_t)NN * FD;
    k_aggr<<<NN, 256, 0, stream>>>(dy0, 0, drow, dsse, l0b1, l0W2, l0b2, du);
    k_bn_stats1<<<NK * BNCH, 256, 0, stream>>>(du, dpart);
    k_bn_stats2<<<1, 128, 0, stream>>>(dpart, l0g, l0be, dbnp);
    k_bn_apply<<<(NN * FD) / 256, 256, 0, stream>>>(du, dbnp, plane1);

    // ---- layer 1 -> plane 2 ----
    float* plane2 = out + (size_t)2 * NN * FD;
    k_y1<<<(NN + 63) / 64, 256, 0, stream>>>(plane1, l1W1, dy1);
    k_aggr<<<NN, 256, 0, stream>>>(dy1, NN * CD, drow, dsse, l1b1, l1W2, l1b2, du);
    k_bn_stats1<<<NK * BNCH, 256, 0, stream>>>(du, dpart);
    k_bn_stats2<<<1, 128, 0, stream>>>(dpart, l1g, l1be, dbnp);
    k_bn_apply<<<(NN * FD) / 256, 256, 0, stream>>>(du, dbnp, plane2);
}

// Round 5
// 429.655 us; speedup vs baseline: 1.4722x; 1.4722x over previous
//
#include <hip/hip_runtime.h>
#include <hip/hip_bf16.h>
#include <math.h>

#define NN 50000
#define NE 800000
#define NK 4
#define FD 128
#define CD 32
#define NCHUNK 196   // ceil(NN/256)
#define BNCH 25      // bn stat chunks
#define BNROWS 2000  // rows per bn chunk (25*2000 = 50000)

typedef unsigned short u16;

__device__ __forceinline__ u16 f2bf(float x) {
    union { float f; unsigned u; } c; c.f = x;
    unsigned r = c.u + 0x7fffu + ((c.u >> 16) & 1u);  // RNE
    return (u16)(r >> 16);
}
__device__ __forceinline__ float bflo(unsigned pair) {   // low bf16 of packed u32
    union { unsigned u; float f; } c; c.u = pair << 16;
    return c.f;
}
__device__ __forceinline__ float bfhi(unsigned pair) {   // high bf16 of packed u32
    union { unsigned u; float f; } c; c.u = pair & 0xffff0000u;
    return c.f;
}

// ---------------- CSR build ----------------

__global__ void k_count(const int* __restrict__ dst, int* __restrict__ count) {
    int i = blockIdx.x * 256 + threadIdx.x;
    if (i < NE) atomicAdd(&count[dst[i]], 1);
}

__global__ void k_chunksum(const int* __restrict__ count, int* __restrict__ csum) {
    __shared__ int s[256];
    int tid = threadIdx.x;
    int i = blockIdx.x * 256 + tid;
    s[tid] = (i < NN) ? count[i] : 0;
    __syncthreads();
    for (int off = 128; off > 0; off >>= 1) {
        if (tid < off) s[tid] += s[tid + off];
        __syncthreads();
    }
    if (tid == 0) csum[blockIdx.x] = s[0];
}

__global__ void k_scan_csum(int* __restrict__ csum) {
    __shared__ int s[256];
    int tid = threadIdx.x;
    int v = (tid < NCHUNK) ? csum[tid] : 0;
    s[tid] = v;
    __syncthreads();
    for (int off = 1; off < 256; off <<= 1) {
        int t = 0;
        if (tid >= off) t = s[tid - off];
        __syncthreads();
        s[tid] += t;
        __syncthreads();
    }
    if (tid < NCHUNK) csum[tid] = s[tid] - v;  // exclusive
}

__global__ void k_scan_final(const int* __restrict__ count, const int* __restrict__ csum,
                             int* __restrict__ rowstart, int* __restrict__ cursor) {
    __shared__ int s[256];
    int tid = threadIdx.x;
    int i = blockIdx.x * 256 + tid;
    int v = (i < NN) ? count[i] : 0;
    s[tid] = v;
    __syncthreads();
    for (int off = 1; off < 256; off <<= 1) {
        int t = 0;
        if (tid >= off) t = s[tid - off];
        __syncthreads();
        s[tid] += t;
        __syncthreads();
    }
    int incl = s[tid];
    int base = csum[blockIdx.x];
    int excl = base + incl - v;
    if (i < NN) {
        rowstart[i] = excl;
        cursor[i] = excl;
        if (i == NN - 1) rowstart[NN] = excl + v;
    }
}

// one packed scattered stream: {src, w01 (bf16 k0|k1), w23 (bf16 k2|k3), pad}
__global__ void k_scatter(const int* __restrict__ src, const int* __restrict__ dst,
                          const float* __restrict__ ew,
                          int* __restrict__ cursor, int4* __restrict__ sse) {
    int e = blockIdx.x * 256 + threadIdx.x;
    if (e < NE) {
        int d = dst[e];
        int p = atomicAdd(&cursor[d], 1);
        unsigned w01 = (unsigned)f2bf(ew[e]) | ((unsigned)f2bf(ew[(size_t)NE + e]) << 16);
        unsigned w23 = (unsigned)f2bf(ew[(size_t)2 * NE + e]) | ((unsigned)f2bf(ew[(size_t)3 * NE + e]) << 16);
        sse[p] = make_int4(src[e], (int)w01, (int)w23, 0);
    }
}

// ---------------- fused encoder + y0 (y0 stored bf16 [N][32]) ----------------

__global__ void __launch_bounds__(256) k_enc_y0(const float* __restrict__ x,
                                                const float* __restrict__ W,
                                                const float* __restrict__ b,
                                                const float* __restrict__ W1,
                                                float* __restrict__ out,
                                                u16* __restrict__ y0) {
    __shared__ float xsT[FD][68];
    int tid = threadIdx.x;
    int nbase = blockIdx.x * 64;

    int r = tid >> 2;
    int cg = (tid & 3) * 32;
    int gn = nbase + r;
    const float* xr = x + (size_t)(gn < NN ? gn : NN - 1) * FD;
#pragma unroll
    for (int q = 0; q < 8; ++q) {
        float4 v = *(const float4*)(xr + cg + q * 4);
        int f = cg + q * 4;
        xsT[f][r] = v.x; xsT[f + 1][r] = v.y; xsT[f + 2][r] = v.z; xsT[f + 3][r] = v.w;
    }
    __syncthreads();

    int cq = (tid & 31) * 4;
    int col = tid & 31;
    int g = tid >> 5;
    float acc[8][4];
    float acy[8];
#pragma unroll
    for (int i = 0; i < 8; ++i) {
        acy[i] = 0.f;
#pragma unroll
        for (int j = 0; j < 4; ++j) acc[i][j] = 0.f;
    }

    for (int f = 0; f < FD; ++f) {
        float4 wv = *(const float4*)(W + f * FD + cq);
        float w1 = W1[f * CD + col];
        float4 xa = *(const float4*)&xsT[f][g * 8];
        float4 xb = *(const float4*)&xsT[f][g * 8 + 4];
        float xn[8] = {xa.x, xa.y, xa.z, xa.w, xb.x, xb.y, xb.z, xb.w};
#pragma unroll
        for (int i = 0; i < 8; ++i) {
            acc[i][0] += xn[i] * wv.x;
            acc[i][1] += xn[i] * wv.y;
            acc[i][2] += xn[i] * wv.z;
            acc[i][3] += xn[i] * wv.w;
            acy[i] += xn[i] * w1;
        }
    }
    float4 bv = *(const float4*)(b + cq);
#pragma unroll
    for (int i = 0; i < 8; ++i) {
        int n = nbase + g * 8 + i;
        if (n < NN) {
            float4 o;
            o.x = acc[i][0] + bv.x;
            o.y = acc[i][1] + bv.y;
            o.z = acc[i][2] + bv.z;
            o.w = acc[i][3] + bv.w;
            *(float4*)(out + (size_t)n * FD + cq) = o;
            y0[(size_t)n * CD + col] = f2bf(acy[i]);
        }
    }
}

// ---------------- y1: per-community h_k @ W1 (32->32), bf16 [N][128] interleaved ----------------

__global__ void __launch_bounds__(256) k_y1(const float* __restrict__ h,
                                            const float* __restrict__ W1,
                                            u16* __restrict__ y1) {
    __shared__ float hsT[FD][68];
    int tid = threadIdx.x;
    int nbase = blockIdx.x * 64;

    int r = tid >> 2;
    int cg = (tid & 3) * 32;
    int gn = nbase + r;
    const float* hr = h + (size_t)(gn < NN ? gn : NN - 1) * FD;
#pragma unroll
    for (int q = 0; q < 8; ++q) {
        float4 v = *(const float4*)(hr + cg + q * 4);
        int f = cg + q * 4;
        hsT[f][r] = v.x; hsT[f + 1][r] = v.y; hsT[f + 2][r] = v.z; hsT[f + 3][r] = v.w;
    }
    __syncthreads();

    int c0 = (tid & 31) * 4;   // 4 output cols within one community (c0 mult of 4)
    int g = tid >> 5;
    int kc = c0 >> 5;
    int jb = c0 & 31;
    float acc[8][4];
#pragma unroll
    for (int i = 0; i < 8; ++i)
#pragma unroll
        for (int j = 0; j < 4; ++j) acc[i][j] = 0.f;

    for (int m = 0; m < CD; ++m) {
        float4 wv = *(const float4*)(W1 + m * CD + jb);
        float4 xa = *(const float4*)&hsT[kc * CD + m][g * 8];
        float4 xb = *(const float4*)&hsT[kc * CD + m][g * 8 + 4];
        float xn[8] = {xa.x, xa.y, xa.z, xa.w, xb.x, xb.y, xb.z, xb.w};
#pragma unroll
        for (int i = 0; i < 8; ++i) {
            acc[i][0] += xn[i] * wv.x;
            acc[i][1] += xn[i] * wv.y;
            acc[i][2] += xn[i] * wv.z;
            acc[i][3] += xn[i] * wv.w;
        }
    }
#pragma unroll
    for (int i = 0; i < 8; ++i) {
        int n = nbase + g * 8 + i;
        if (n < NN) {
            unsigned lo = (unsigned)f2bf(acc[i][0]) | ((unsigned)f2bf(acc[i][1]) << 16);
            unsigned hi = (unsigned)f2bf(acc[i][2]) | ((unsigned)f2bf(acc[i][3]) << 16);
            *(uint2*)(y1 + (size_t)n * FD + c0) = make_uint2(lo, hi);
        }
    }
}

// ---------------- fused aggregation + relu + MLP2 ----------------
// wave = node, ALL 4 communities per edge visit (amortize sse load).
// lane: k = lane>>4 (community), f0 = (lane&15)*2 (feature pair).
// STRIDE=32: y [N][32] bf16 shared across k. STRIDE=128: y [N][128] bf16, col k*32+f0.
// Per edge: one broadcast int4 (src + 4 bf16 weights), one u32 gather/lane (wave
// collectively reads exactly the 64B/256B src row), 2 FMA/lane.

template <int STRIDE>
__global__ void __launch_bounds__(256) k_aggr(const u16* __restrict__ y,
                                              const int* __restrict__ row,
                                              const int4* __restrict__ sse,
                                              const float* __restrict__ b1,
                                              const float* __restrict__ W2,
                                              const float* __restrict__ b2,
                                              float* __restrict__ u) {
    __shared__ float tsh[4][NK][CD + 1];
    __shared__ float W2s[CD][CD];
    __shared__ float b2s[CD];
    int tid = threadIdx.x;
    for (int i = tid; i < CD * CD; i += 256) W2s[i >> 5][i & 31] = W2[i];
    if (tid < CD) b2s[tid] = b2[tid];
    __syncthreads();

    int w = tid >> 6;
    int lane = tid & 63;
    int node = blockIdx.x * 4 + w;   // NN divisible by 4

    int k = lane >> 4;
    int f0 = (lane & 15) * 2;
    int col = (STRIDE == CD) ? f0 : (k * CD + f0);
    const u16* yb = y + col;

    float a0 = 0.f, a1 = 0.f;
    int beg = row[node], end = row[node + 1];
    for (int j0 = beg; j0 < end; j0 += 8) {
        int ss[8];
        float ww[8];
#pragma unroll
        for (int q = 0; q < 8; ++q) {
            int jj = j0 + q;
            bool ok = jj < end;
            int jc = ok ? jj : beg;
            int4 ee = sse[jc];
            ss[q] = ee.x;
            unsigned wp = (k < 2) ? (unsigned)ee.y : (unsigned)ee.z;
            float wv = (k & 1) ? bfhi(wp) : bflo(wp);
            ww[q] = ok ? wv : 0.f;
        }
#pragma unroll
        for (int q = 0; q < 8; ++q) {
            unsigned pv = *(const unsigned*)(yb + (size_t)ss[q] * STRIDE);
            a0 += ww[q] * bflo(pv);
            a1 += ww[q] * bfhi(pv);
        }
    }
    unsigned hv = *(const unsigned*)(yb + (size_t)node * STRIDE);
    float2 bv = *(const float2*)(b1 + f0);
    tsh[w][k][f0]     = fmaxf(bflo(hv) + a0 + bv.x, 0.f);
    tsh[w][k][f0 + 1] = fmaxf(bfhi(hv) + a1 + bv.y, 0.f);
    __threadfence_block();  // wave-local LDS visibility (no cross-wave sharing)

    int j = lane & 31;
    int kA = lane >> 5, kB = kA + 2;
    float uA = b2s[j], uB = uA;
#pragma unroll 4
    for (int m = 0; m < CD; ++m) {
        float w2 = W2s[m][j];
        uA += tsh[w][kA][m] * w2;
        uB += tsh[w][kB][m] * w2;
    }
    u[((size_t)kA * NN + node) * CD + j] = uA;
    u[((size_t)kB * NN + node) * CD + j] = uB;
}

// ---------------- batchnorm (two-stage, deterministic) ----------------

__global__ void __launch_bounds__(256) k_bn_stats1(const float* __restrict__ u,
                                                   float* __restrict__ part) {
    int k = blockIdx.x & 3;
    int ch = blockIdx.x >> 2;
    int f = threadIdx.x & 31;
    int rg = threadIdx.x >> 5;
    float s1 = 0.f, s2 = 0.f;
    int nend = (ch + 1) * BNROWS;
    if (nend > NN) nend = NN;
    for (int n = ch * BNROWS + rg; n < nend; n += 8) {
        float v = u[((size_t)k * NN + n) * CD + f];
        s1 += v;
        s2 += v * v;
    }
    __shared__ float sh1[8][32], sh2[8][32];
    sh1[rg][f] = s1;
    sh2[rg][f] = s2;
    __syncthreads();
    if (rg == 0) {
#pragma unroll
        for (int r = 1; r < 8; ++r) {
            s1 += sh1[r][f];
            s2 += sh2[r][f];
        }
        part[(((size_t)k * BNCH + ch) * CD + f) * 2] = s1;
        part[(((size_t)k * BNCH + ch) * CD + f) * 2 + 1] = s2;
    }
}

__global__ void k_bn_stats2(const float* __restrict__ part, const float* __restrict__ gamma,
                            const float* __restrict__ beta, float* __restrict__ bnp) {
    int c = threadIdx.x;  // 0..127
    int k = c >> 5, f = c & 31;
    float S1 = 0.f, S2 = 0.f;
    for (int ch = 0; ch < BNCH; ++ch) {
        S1 += part[(((size_t)k * BNCH + ch) * CD + f) * 2];
        S2 += part[(((size_t)k * BNCH + ch) * CD + f) * 2 + 1];
    }
    float mean = S1 / (float)NN;
    float var = S2 / (float)NN - mean * mean;
    float scale = gamma[f] * rsqrtf(var + 1e-5f);
    bnp[c * 2] = scale;
    bnp[c * 2 + 1] = beta[f] - mean * scale;
}

__global__ void __launch_bounds__(256) k_bn_apply(const float* __restrict__ u,
                                                  const float* __restrict__ bnp,
                                                  float* __restrict__ out) {
    int idx = blockIdx.x * 256 + threadIdx.x;  // over NN*FD
    int n = idx >> 7;
    int c = idx & 127;
    int k = c >> 5, f = c & 31;
    float v = u[((size_t)k * NN + n) * CD + f];
    out[idx] = fmaxf(fmaf(v, bnp[c * 2], bnp[c * 2 + 1]), 0.f);
}

// ---------------- launch ----------------

extern "C" void kernel_launch(void* const* d_in, const int* in_sizes, int n_in,
                              void* d_out, int out_size, void* d_ws, size_t ws_size,
                              hipStream_t stream) {
    const float* x = (const float*)d_in[0];
    const int* ei = (const int*)d_in[1];
    const float* ew = (const float*)d_in[2];
    const float* l0W1 = (const float*)d_in[3];
    const float* l0b1 = (const float*)d_in[4];
    const float* l0W2 = (const float*)d_in[5];
    const float* l0b2 = (const float*)d_in[6];
    const float* l0g = (const float*)d_in[7];
    const float* l0be = (const float*)d_in[8];
    const float* l1W1 = (const float*)d_in[9];
    const float* l1b1 = (const float*)d_in[10];
    const float* l1W2 = (const float*)d_in[11];
    const float* l1b2 = (const float*)d_in[12];
    const float* l1g = (const float*)d_in[13];
    const float* l1be = (const float*)d_in[14];
    const float* encW = (const float*)d_in[15];
    const float* encb = (const float*)d_in[16];
    float* out = (float*)d_out;

    char* ws = (char*)d_ws;
    size_t off = 0;
    auto alloc = [&](size_t bytes) -> void* {
        void* p = ws + off;
        off += (bytes + 255) & ~(size_t)255;
        return p;
    };
    int* dcount = (int*)alloc((size_t)NN * 4);
    int* drow = (int*)alloc((size_t)(NN + 1) * 4);
    int* dcur = (int*)alloc((size_t)NN * 4);
    int* dcsum = (int*)alloc(256 * 4);
    int4* dsse = (int4*)alloc((size_t)NE * 16);
    u16* dy0 = (u16*)alloc((size_t)NN * CD * 2);            // bf16 y0 (3.2MB)
    u16* dy1 = (u16*)alloc((size_t)NN * FD * 2);            // bf16 y1 interleaved (12.8MB)
    float* du = (float*)alloc((size_t)NK * NN * CD * 4);    // MLP2 out (fp32)
    float* dpart = (float*)alloc((size_t)NK * BNCH * CD * 2 * 4);
    float* dbnp = (float*)alloc((size_t)FD * 2 * 4);

    const int* src = ei;
    const int* dst = ei + NE;

    // CSR build + packed (src, weights) scatter
    hipMemsetAsync(dcount, 0, (size_t)NN * 4, stream);
    k_count<<<(NE + 255) / 256, 256, 0, stream>>>(dst, dcount);
    k_chunksum<<<NCHUNK, 256, 0, stream>>>(dcount, dcsum);
    k_scan_csum<<<1, 256, 0, stream>>>(dcsum);
    k_scan_final<<<NCHUNK, 256, 0, stream>>>(dcount, dcsum, drow, dcur);
    k_scatter<<<(NE + 255) / 256, 256, 0, stream>>>(src, dst, ew, dcur, dsse);

    // plane 0 + y0
    k_enc_y0<<<(NN + 63) / 64, 256, 0, stream>>>(x, encW, encb, l0W1, out, dy0);

    // ---- layer 0 -> plane 1 ----
    float* plane1 = out + (size_t)NN * FD;
    k_aggr<CD><<<NN / 4, 256, 0, stream>>>(dy0, drow, dsse, l0b1, l0W2, l0b2, du);
    k_bn_stats1<<<NK * BNCH, 256, 0, stream>>>(du, dpart);
    k_bn_stats2<<<1, 128, 0, stream>>>(dpart, l0g, l0be, dbnp);
    k_bn_apply<<<(NN * FD) / 256, 256, 0, stream>>>(du, dbnp, plane1);

    // ---- layer 1 -> plane 2 ----
    float* plane2 = out + (size_t)2 * NN * FD;
    k_y1<<<(NN + 63) / 64, 256, 0, stream>>>(plane1, l1W1, dy1);
    k_aggr<FD><<<NN / 4, 256, 0, stream>>>(dy1, drow, dsse, l1b1, l1W2, l1b2, du);
    k_bn_stats1<<<NK * BNCH, 256, 0, stream>>>(du, dpart);
    k_bn_stats2<<<1, 128, 0, stream>>>(dpart, l1g, l1be, dbnp);
    k_bn_apply<<<(NN * FD) / 256, 256, 0, stream>>>(du, dbnp, plane2);
}

// Round 6
// 345.124 us; speedup vs baseline: 1.8328x; 1.2449x over previous
//
#include <hip/hip_runtime.h>
#include <hip/hip_bf16.h>
#include <math.h>

#define NN 50000
#define NE 800000
#define NK 4
#define FD 128
#define CD 32
#define NCHUNK 196   // ceil(NN/256)
#define BNCH 500     // bn stat chunks (2000 blocks total)
#define BNROWS 100   // rows per bn chunk (500*100 = 50000)

typedef unsigned short u16;

__device__ __forceinline__ u16 f2bf(float x) {
    union { float f; unsigned u; } c; c.f = x;
    unsigned r = c.u + 0x7fffu + ((c.u >> 16) & 1u);  // RNE
    return (u16)(r >> 16);
}
__device__ __forceinline__ float bflo(unsigned pair) {   // low bf16 of packed u32
    union { unsigned u; float f; } c; c.u = pair << 16;
    return c.f;
}
__device__ __forceinline__ float bfhi(unsigned pair) {   // high bf16 of packed u32
    union { unsigned u; float f; } c; c.u = pair & 0xffff0000u;
    return c.f;
}

// ---------------- CSR build ----------------

__global__ void k_count(const int* __restrict__ dst, int* __restrict__ count) {
    int i = blockIdx.x * 256 + threadIdx.x;
    if (i < NE) atomicAdd(&count[dst[i]], 1);
}

__global__ void k_chunksum(const int* __restrict__ count, int* __restrict__ csum) {
    __shared__ int s[256];
    int tid = threadIdx.x;
    int i = blockIdx.x * 256 + tid;
    s[tid] = (i < NN) ? count[i] : 0;
    __syncthreads();
    for (int off = 128; off > 0; off >>= 1) {
        if (tid < off) s[tid] += s[tid + off];
        __syncthreads();
    }
    if (tid == 0) csum[blockIdx.x] = s[0];
}

__global__ void k_scan_csum(int* __restrict__ csum) {
    __shared__ int s[256];
    int tid = threadIdx.x;
    int v = (tid < NCHUNK) ? csum[tid] : 0;
    s[tid] = v;
    __syncthreads();
    for (int off = 1; off < 256; off <<= 1) {
        int t = 0;
        if (tid >= off) t = s[tid - off];
        __syncthreads();
        s[tid] += t;
        __syncthreads();
    }
    if (tid < NCHUNK) csum[tid] = s[tid] - v;  // exclusive
}

__global__ void k_scan_final(const int* __restrict__ count, const int* __restrict__ csum,
                             int* __restrict__ rowstart, int* __restrict__ cursor) {
    __shared__ int s[256];
    int tid = threadIdx.x;
    int i = blockIdx.x * 256 + tid;
    int v = (i < NN) ? count[i] : 0;
    s[tid] = v;
    __syncthreads();
    for (int off = 1; off < 256; off <<= 1) {
        int t = 0;
        if (tid >= off) t = s[tid - off];
        __syncthreads();
        s[tid] += t;
        __syncthreads();
    }
    int incl = s[tid];
    int base = csum[blockIdx.x];
    int excl = base + incl - v;
    if (i < NN) {
        rowstart[i] = excl;
        cursor[i] = excl;
        if (i == NN - 1) rowstart[NN] = excl + v;
    }
}

// one packed scattered stream: {src, w01 (bf16 k0|k1), w23 (bf16 k2|k3), pad}
__global__ void k_scatter(const int* __restrict__ src, const int* __restrict__ dst,
                          const float* __restrict__ ew,
                          int* __restrict__ cursor, int4* __restrict__ sse) {
    int e = blockIdx.x * 256 + threadIdx.x;
    if (e < NE) {
        int d = dst[e];
        int p = atomicAdd(&cursor[d], 1);
        unsigned w01 = (unsigned)f2bf(ew[e]) | ((unsigned)f2bf(ew[(size_t)NE + e]) << 16);
        unsigned w23 = (unsigned)f2bf(ew[(size_t)2 * NE + e]) | ((unsigned)f2bf(ew[(size_t)3 * NE + e]) << 16);
        sse[p] = make_int4(src[e], (int)w01, (int)w23, 0);
    }
}

// ---------------- fused encoder + y0 (y0 stored bf16 [N][32]) ----------------

__global__ void __launch_bounds__(256) k_enc_y0(const float* __restrict__ x,
                                                const float* __restrict__ W,
                                                const float* __restrict__ b,
                                                const float* __restrict__ W1,
                                                float* __restrict__ out,
                                                u16* __restrict__ y0) {
    __shared__ float xsT[FD][68];
    int tid = threadIdx.x;
    int nbase = blockIdx.x * 64;

    int r = tid >> 2;
    int cg = (tid & 3) * 32;
    int gn = nbase + r;
    const float* xr = x + (size_t)(gn < NN ? gn : NN - 1) * FD;
#pragma unroll
    for (int q = 0; q < 8; ++q) {
        float4 v = *(const float4*)(xr + cg + q * 4);
        int f = cg + q * 4;
        xsT[f][r] = v.x; xsT[f + 1][r] = v.y; xsT[f + 2][r] = v.z; xsT[f + 3][r] = v.w;
    }
    __syncthreads();

    int cq = (tid & 31) * 4;
    int col = tid & 31;
    int g = tid >> 5;
    float acc[8][4];
    float acy[8];
#pragma unroll
    for (int i = 0; i < 8; ++i) {
        acy[i] = 0.f;
#pragma unroll
        for (int j = 0; j < 4; ++j) acc[i][j] = 0.f;
    }

    for (int f = 0; f < FD; ++f) {
        float4 wv = *(const float4*)(W + f * FD + cq);
        float w1 = W1[f * CD + col];
        float4 xa = *(const float4*)&xsT[f][g * 8];
        float4 xb = *(const float4*)&xsT[f][g * 8 + 4];
        float xn[8] = {xa.x, xa.y, xa.z, xa.w, xb.x, xb.y, xb.z, xb.w};
#pragma unroll
        for (int i = 0; i < 8; ++i) {
            acc[i][0] += xn[i] * wv.x;
            acc[i][1] += xn[i] * wv.y;
            acc[i][2] += xn[i] * wv.z;
            acc[i][3] += xn[i] * wv.w;
            acy[i] += xn[i] * w1;
        }
    }
    float4 bv = *(const float4*)(b + cq);
#pragma unroll
    for (int i = 0; i < 8; ++i) {
        int n = nbase + g * 8 + i;
        if (n < NN) {
            float4 o;
            o.x = acc[i][0] + bv.x;
            o.y = acc[i][1] + bv.y;
            o.z = acc[i][2] + bv.z;
            o.w = acc[i][3] + bv.w;
            *(float4*)(out + (size_t)n * FD + cq) = o;
            y0[(size_t)n * CD + col] = f2bf(acy[i]);
        }
    }
}

// ---------------- y1: per-community h_k @ W1 (32->32), bf16 [N][128] interleaved ----------------

__global__ void __launch_bounds__(256) k_y1(const float* __restrict__ h,
                                            const float* __restrict__ W1,
                                            u16* __restrict__ y1) {
    __shared__ float hsT[FD][68];
    int tid = threadIdx.x;
    int nbase = blockIdx.x * 64;

    int r = tid >> 2;
    int cg = (tid & 3) * 32;
    int gn = nbase + r;
    const float* hr = h + (size_t)(gn < NN ? gn : NN - 1) * FD;
#pragma unroll
    for (int q = 0; q < 8; ++q) {
        float4 v = *(const float4*)(hr + cg + q * 4);
        int f = cg + q * 4;
        hsT[f][r] = v.x; hsT[f + 1][r] = v.y; hsT[f + 2][r] = v.z; hsT[f + 3][r] = v.w;
    }
    __syncthreads();

    int c0 = (tid & 31) * 4;   // 4 output cols within one community (c0 mult of 4)
    int g = tid >> 5;
    int kc = c0 >> 5;
    int jb = c0 & 31;
    float acc[8][4];
#pragma unroll
    for (int i = 0; i < 8; ++i)
#pragma unroll
        for (int j = 0; j < 4; ++j) acc[i][j] = 0.f;

    for (int m = 0; m < CD; ++m) {
        float4 wv = *(const float4*)(W1 + m * CD + jb);
        float4 xa = *(const float4*)&hsT[kc * CD + m][g * 8];
        float4 xb = *(const float4*)&hsT[kc * CD + m][g * 8 + 4];
        float xn[8] = {xa.x, xa.y, xa.z, xa.w, xb.x, xb.y, xb.z, xb.w};
#pragma unroll
        for (int i = 0; i < 8; ++i) {
            acc[i][0] += xn[i] * wv.x;
            acc[i][1] += xn[i] * wv.y;
            acc[i][2] += xn[i] * wv.z;
            acc[i][3] += xn[i] * wv.w;
        }
    }
#pragma unroll
    for (int i = 0; i < 8; ++i) {
        int n = nbase + g * 8 + i;
        if (n < NN) {
            unsigned lo = (unsigned)f2bf(acc[i][0]) | ((unsigned)f2bf(acc[i][1]) << 16);
            unsigned hi = (unsigned)f2bf(acc[i][2]) | ((unsigned)f2bf(acc[i][3]) << 16);
            *(uint2*)(y1 + (size_t)n * FD + c0) = make_uint2(lo, hi);
        }
    }
}

// ---------------- fused aggregation + relu + MLP2 ----------------
// wave = node, ALL 4 communities per edge visit (amortize sse load).
// lane: k = lane>>4 (community), f0 = (lane&15)*2 (feature pair).

template <int STRIDE>
__global__ void __launch_bounds__(256) k_aggr(const u16* __restrict__ y,
                                              const int* __restrict__ row,
                                              const int4* __restrict__ sse,
                                              const float* __restrict__ b1,
                                              const float* __restrict__ W2,
                                              const float* __restrict__ b2,
                                              float* __restrict__ u) {
    __shared__ float tsh[4][NK][CD + 1];
    __shared__ float W2s[CD][CD];
    __shared__ float b2s[CD];
    int tid = threadIdx.x;
    for (int i = tid; i < CD * CD; i += 256) W2s[i >> 5][i & 31] = W2[i];
    if (tid < CD) b2s[tid] = b2[tid];
    __syncthreads();

    int w = tid >> 6;
    int lane = tid & 63;
    int node = blockIdx.x * 4 + w;   // NN divisible by 4

    int k = lane >> 4;
    int f0 = (lane & 15) * 2;
    int col = (STRIDE == CD) ? f0 : (k * CD + f0);
    const u16* yb = y + col;

    float a0 = 0.f, a1 = 0.f;
    int beg = row[node], end = row[node + 1];
    for (int j0 = beg; j0 < end; j0 += 8) {
        int ss[8];
        float ww[8];
#pragma unroll
        for (int q = 0; q < 8; ++q) {
            int jj = j0 + q;
            bool ok = jj < end;
            int jc = ok ? jj : beg;
            int4 ee = sse[jc];
            ss[q] = ee.x;
            unsigned wp = (k < 2) ? (unsigned)ee.y : (unsigned)ee.z;
            float wv = (k & 1) ? bfhi(wp) : bflo(wp);
            ww[q] = ok ? wv : 0.f;
        }
#pragma unroll
        for (int q = 0; q < 8; ++q) {
            unsigned pv = *(const unsigned*)(yb + (size_t)ss[q] * STRIDE);
            a0 += ww[q] * bflo(pv);
            a1 += ww[q] * bfhi(pv);
        }
    }
    unsigned hv = *(const unsigned*)(yb + (size_t)node * STRIDE);
    float2 bv = *(const float2*)(b1 + f0);
    tsh[w][k][f0]     = fmaxf(bflo(hv) + a0 + bv.x, 0.f);
    tsh[w][k][f0 + 1] = fmaxf(bfhi(hv) + a1 + bv.y, 0.f);
    __threadfence_block();  // wave-local LDS visibility (no cross-wave sharing)

    int j = lane & 31;
    int kA = lane >> 5, kB = kA + 2;
    float uA = b2s[j], uB = uA;
#pragma unroll 4
    for (int m = 0; m < CD; ++m) {
        float w2 = W2s[m][j];
        uA += tsh[w][kA][m] * w2;
        uB += tsh[w][kB][m] * w2;
    }
    u[((size_t)kA * NN + node) * CD + j] = uA;
    u[((size_t)kB * NN + node) * CD + j] = uB;
}

// ---------------- batchnorm (two-stage, deterministic) ----------------
// stage 1: 2000 blocks (4 communities x 500 chunks of 100 rows)

__global__ void __launch_bounds__(256) k_bn_stats1(const float* __restrict__ u,
                                                   float* __restrict__ part) {
    int k = blockIdx.x & 3;
    int ch = blockIdx.x >> 2;
    int f = threadIdx.x & 31;
    int rg = threadIdx.x >> 5;
    float s1 = 0.f, s2 = 0.f;
    int nend = (ch + 1) * BNROWS;
    for (int n = ch * BNROWS + rg; n < nend; n += 8) {
        float v = u[((size_t)k * NN + n) * CD + f];
        s1 += v;
        s2 += v * v;
    }
    __shared__ float sh1[8][32], sh2[8][32];
    sh1[rg][f] = s1;
    sh2[rg][f] = s2;
    __syncthreads();
    if (rg == 0) {
#pragma unroll
        for (int r = 1; r < 8; ++r) {
            s1 += sh1[r][f];
            s2 += sh2[r][f];
        }
        part[(((size_t)k * BNCH + ch) * CD + f) * 2] = s1;
        part[(((size_t)k * BNCH + ch) * CD + f) * 2 + 1] = s2;
    }
}

__global__ void k_bn_stats2(const float* __restrict__ part, const float* __restrict__ gamma,
                            const float* __restrict__ beta, float* __restrict__ bnp) {
    int c = threadIdx.x;  // 0..127
    int k = c >> 5, f = c & 31;
    float S1 = 0.f, S2 = 0.f;
    for (int ch = 0; ch < BNCH; ++ch) {
        float2 p = *(const float2*)(part + (((size_t)k * BNCH + ch) * CD + f) * 2);
        S1 += p.x;
        S2 += p.y;
    }
    float mean = S1 / (float)NN;
    float var = S2 / (float)NN - mean * mean;
    float scale = gamma[f] * rsqrtf(var + 1e-5f);
    bnp[c * 2] = scale;
    bnp[c * 2 + 1] = beta[f] - mean * scale;
}

// float4-vectorized: thread = (node, one float4 of the 128 cols)
__global__ void __launch_bounds__(256) k_bn_apply(const float* __restrict__ u,
                                                  const float* __restrict__ bnp,
                                                  float* __restrict__ out) {
    int gid = blockIdx.x * 256 + threadIdx.x;  // over NN*FD/4
    int n = gid >> 5;
    int q = gid & 31;
    int c0 = q * 4;
    int k = c0 >> 5, f = c0 & 31;
    float4 v = *(const float4*)(u + ((size_t)k * NN + n) * CD + f);
    float4 s0 = *(const float4*)(bnp + c0 * 2);       // {sc0, sh0, sc1, sh1}
    float4 s1 = *(const float4*)(bnp + c0 * 2 + 4);   // {sc2, sh2, sc3, sh3}
    float4 o;
    o.x = fmaxf(fmaf(v.x, s0.x, s0.y), 0.f);
    o.y = fmaxf(fmaf(v.y, s0.z, s0.w), 0.f);
    o.z = fmaxf(fmaf(v.z, s1.x, s1.y), 0.f);
    o.w = fmaxf(fmaf(v.w, s1.z, s1.w), 0.f);
    *(float4*)(out + (size_t)n * FD + c0) = o;
}

// ---------------- launch ----------------

extern "C" void kernel_launch(void* const* d_in, const int* in_sizes, int n_in,
                              void* d_out, int out_size, void* d_ws, size_t ws_size,
                              hipStream_t stream) {
    const float* x = (const float*)d_in[0];
    const int* ei = (const int*)d_in[1];
    const float* ew = (const float*)d_in[2];
    const float* l0W1 = (const float*)d_in[3];
    const float* l0b1 = (const float*)d_in[4];
    const float* l0W2 = (const float*)d_in[5];
    const float* l0b2 = (const float*)d_in[6];
    const float* l0g = (const float*)d_in[7];
    const float* l0be = (const float*)d_in[8];
    const float* l1W1 = (const float*)d_in[9];
    const float* l1b1 = (const float*)d_in[10];
    const float* l1W2 = (const float*)d_in[11];
    const float* l1b2 = (const float*)d_in[12];
    const float* l1g = (const float*)d_in[13];
    const float* l1be = (const float*)d_in[14];
    const float* encW = (const float*)d_in[15];
    const float* encb = (const float*)d_in[16];
    float* out = (float*)d_out;

    char* ws = (char*)d_ws;
    size_t off = 0;
    auto alloc = [&](size_t bytes) -> void* {
        void* p = ws + off;
        off += (bytes + 255) & ~(size_t)255;
        return p;
    };
    int* dcount = (int*)alloc((size_t)NN * 4);
    int* drow = (int*)alloc((size_t)(NN + 1) * 4);
    int* dcur = (int*)alloc((size_t)NN * 4);
    int* dcsum = (int*)alloc(256 * 4);
    int4* dsse = (int4*)alloc((size_t)NE * 16);
    u16* dy0 = (u16*)alloc((size_t)NN * CD * 2);            // bf16 y0 (3.2MB)
    u16* dy1 = (u16*)alloc((size_t)NN * FD * 2);            // bf16 y1 interleaved (12.8MB)
    float* du = (float*)alloc((size_t)NK * NN * CD * 4);    // MLP2 out (fp32)
    float* dpart = (float*)alloc((size_t)NK * BNCH * CD * 2 * 4);  // 512KB
    float* dbnp = (float*)alloc((size_t)FD * 2 * 4);

    const int* src = ei;
    const int* dst = ei + NE;

    // CSR build + packed (src, weights) scatter
    hipMemsetAsync(dcount, 0, (size_t)NN * 4, stream);
    k_count<<<(NE + 255) / 256, 256, 0, stream>>>(dst, dcount);
    k_chunksum<<<NCHUNK, 256, 0, stream>>>(dcount, dcsum);
    k_scan_csum<<<1, 256, 0, stream>>>(dcsum);
    k_scan_final<<<NCHUNK, 256, 0, stream>>>(dcount, dcsum, drow, dcur);
    k_scatter<<<(NE + 255) / 256, 256, 0, stream>>>(src, dst, ew, dcur, dsse);

    // plane 0 + y0
    k_enc_y0<<<(NN + 63) / 64, 256, 0, stream>>>(x, encW, encb, l0W1, out, dy0);

    // ---- layer 0 -> plane 1 ----
    float* plane1 = out + (size_t)NN * FD;
    k_aggr<CD><<<NN / 4, 256, 0, stream>>>(dy0, drow, dsse, l0b1, l0W2, l0b2, du);
    k_bn_stats1<<<NK * BNCH, 256, 0, stream>>>(du, dpart);
    k_bn_stats2<<<1, 128, 0, stream>>>(dpart, l0g, l0be, dbnp);
    k_bn_apply<<<(NN * FD) / 1024, 256, 0, stream>>>(du, dbnp, plane1);

    // ---- layer 1 -> plane 2 ----
    float* plane2 = out + (size_t)2 * NN * FD;
    k_y1<<<(NN + 63) / 64, 256, 0, stream>>>(plane1, l1W1, dy1);
    k_aggr<FD><<<NN / 4, 256, 0, stream>>>(dy1, drow, dsse, l1b1, l1W2, l1b2, du);
    k_bn_stats1<<<NK * BNCH, 256, 0, stream>>>(du, dpart);
    k_bn_stats2<<<1, 128, 0, stream>>>(dpart, l1g, l1be, dbnp);
    k_bn_apply<<<(NN * FD) / 1024, 256, 0, stream>>>(du, dbnp, plane2);
}